// Round 5
// baseline (147.332 us; speedup 1.0000x reference)
//
#include <hip/hip_runtime.h>
#include <stdint.h>

#define COLS      8192
#define KP1       33          // k+1
#define CAP       1024        // candidate buffer capacity (mean ~100 at T=2.25)
#define NTHREADS  256
#define TVAL      2.25f       // fixed prune threshold; exact tier-2 guards misuse
// Masked-fill sentinel: largest-magnitude negative value exactly representable
// in bf16 (-3.3895314e38). Its f32->bf16 cast stays FINITE (harness compares in
// bf16 domain; -FLT_MAX rounds to -inf there -> (-inf)-(-inf)=NaN -> fail).
#define NEGF_BITS 0xFF7F0000u
#define POSF_BITS 0x7F7F0000u

// Monotone key: unsigned compare on key == float compare on value.
__device__ __forceinline__ unsigned f2k(float f) {
    unsigned u = __float_as_uint(f);
    return u ^ ((unsigned)((int)u >> 31) | 0x80000000u);
}
__device__ __forceinline__ float k2f(unsigned k) {
    unsigned m = (unsigned)((int)k >> 31);
    return __uint_as_float(k ^ (0x80000000u | ~m));
}
// Decode, clamping non-finite to the sign-matched largest bf16-finite value.
// (Writing ANY +/-inf makes the harness's inf-inf = NaN -> must never emit inf.)
__device__ __forceinline__ float k2f_finite(unsigned k) {
    float f = k2f(k);
    unsigned u = __float_as_uint(f);
    if ((u & 0x7F800000u) == 0x7F800000u)
        f = __uint_as_float((u & 0x80000000u) ? NEGF_BITS : POSF_BITS);
    return f;
}

// ---------------- Kernel A: pure write-stream fill (direction-pure ~7 TB/s) --
__global__ __launch_bounds__(NTHREADS)
void fill_kernel(float4* __restrict__ out, int n4) {
    const float NEGF = __uint_as_float(NEGF_BITS);
    const float4 nf4 = make_float4(NEGF, NEGF, NEGF, NEGF);
    int stride = gridDim.x * NTHREADS;
    for (int i = blockIdx.x * NTHREADS + threadIdx.x; i < n4; i += stride)
        out[i] = nf4;
}

// ---------------- Kernel B: read row, select top-33, scatter ---------------
__global__ __launch_bounds__(NTHREADS, 6)
void select_kernel(const float* __restrict__ sim, float* __restrict__ out, int nrows) {
    const int row  = blockIdx.x;
    if (row >= nrows) return;
    const int tid  = threadIdx.x;
    const int lane = tid & 63;
    const int wid  = tid >> 6;
    const size_t rbase = (size_t)row * COLS;

    __shared__ unsigned s_key[CAP];
    __shared__ unsigned s_idx[CAP];
    __shared__ unsigned s_nc;
    __shared__ unsigned long long s_red[4];

    // Load row: 8 coalesced float4 per thread -> 32 registers, static indexing.
    const float4* rp = (const float4*)(sim + rbase);
    float f[32];
#pragma unroll
    for (int i = 0; i < 8; ++i) {
        float4 t = rp[i * NTHREADS + tid];
        f[i * 4 + 0] = t.x; f[i * 4 + 1] = t.y;
        f[i * 4 + 2] = t.z; f[i * 4 + 3] = t.w;
    }
    if (tid == 0) s_nc = 0;
    __syncthreads();   // s_nc visible; loads drained (needed before use anyway)

    // Ballot-compact candidates (x > T, NaN-inclusive via !(x<=T)) into LDS.
    // element index: f[j] holds column ((j>>2)<<10) + tid*4 + (j&3).
#pragma unroll
    for (int j = 0; j < 32; ++j) {
        bool pred = !(f[j] <= TVAL);
        unsigned long long m = __ballot(pred);
        if (m == 0ull) continue;                 // scalar branch, wave-uniform
        unsigned base = 0;
        if (lane == 0) base = atomicAdd(&s_nc, (unsigned)__popcll(m));
        base = __shfl(base, 0, 64);
        if (pred) {
            unsigned off = __builtin_amdgcn_mbcnt_hi(
                               (unsigned)(m >> 32),
                               __builtin_amdgcn_mbcnt_lo((unsigned)m, 0u));
            unsigned pos = base + off;
            if (pos < CAP) {
                s_key[pos] = f2k(f[j]);
                s_idx[pos] = (unsigned)(((j >> 2) << 10) + tid * 4 + (j & 3));
            }
        }
    }
    __syncthreads();
    unsigned nc = s_nc;   // block-uniform

    if (nc >= KP1 && nc <= CAP) {
        // Fast path: rank candidates (key desc, index asc = jax.lax.top_k ties),
        // scatter the 33 winners. LDS reads are same-address broadcasts.
        for (unsigned mi = tid; mi < nc; mi += NTHREADS) {
            unsigned myk = s_key[mi];
            unsigned myi = s_idx[mi];
            unsigned r = 0, el = 0;
            for (unsigned q = 0; q < nc; ++q) {
                unsigned qk = s_key[q];
                r  += (qk > myk) ? 1u : 0u;
                el += ((qk == myk) && (s_idx[q] < myi)) ? 1u : 0u;
            }
            if (r + el < KP1) out[rbase + (myi & (COLS - 1))] = k2f_finite(myk);
        }
    } else {
        // Tier 2 (exact for ANY input; statistically unreachable for Gaussian):
        // 33x block-wide max extraction over the register-resident row.
        unsigned selmask = 0;
        for (int s = 0; s < KP1; ++s) {
            unsigned long long best = 0ull;
#pragma unroll
            for (int j = 0; j < 32; ++j) {
                if (!((selmask >> j) & 1u)) {
                    unsigned idx = (unsigned)(((j >> 2) << 10) + tid * 4 + (j & 3));
                    unsigned long long p =
                        ((unsigned long long)f2k(f[j]) << 32) | (0xFFFFFFFFu - idx);
                    if (p > best) best = p;
                }
            }
#pragma unroll
            for (int d = 1; d < 64; d <<= 1) {
                unsigned long long o = __shfl_xor(best, d, 64);
                if (o > best) best = o;
            }
            if (lane == 0) s_red[wid] = best;
            __syncthreads();
            unsigned long long gb = s_red[0];
            if (s_red[1] > gb) gb = s_red[1];
            if (s_red[2] > gb) gb = s_red[2];
            if (s_red[3] > gb) gb = s_red[3];
            unsigned gidx = (0xFFFFFFFFu - (unsigned)(gb & 0xFFFFFFFFu)) & (COLS - 1);
            unsigned gkey = (unsigned)(gb >> 32);
            if (((gidx >> 2) & 255u) == (unsigned)tid) {   // owner thread
                unsigned j = ((gidx >> 10) << 2) | (gidx & 3u);
                selmask |= (1u << j);
                out[rbase + gidx] = k2f_finite(gkey);
            }
            __syncthreads();
        }
    }
}

extern "C" void kernel_launch(void* const* d_in, const int* in_sizes, int n_in,
                              void* d_out, int out_size, void* d_ws, size_t ws_size,
                              hipStream_t stream) {
    const float* sim = (const float*)d_in[0];
    float* out = (float*)d_out;
    int rows = in_sizes[0] / COLS;
    int n4 = out_size / 4;   // float4 count
    hipLaunchKernelGGL(fill_kernel, dim3(4096), dim3(NTHREADS), 0, stream,
                       (float4*)out, n4);
    hipLaunchKernelGGL(select_kernel, dim3(rows), dim3(NTHREADS), 0, stream,
                       sim, out, rows);
}

// Round 6
// 116.316 us; speedup vs baseline: 1.2667x; 1.2667x over previous
//
#include <hip/hip_runtime.h>
#include <stdint.h>

#define COLS      8192
#define KP1       33          // k+1
#define CAP       1024        // candidate capacity (mean ~100 at T=2.25)
#define NTHREADS  256
#define TVAL      2.25f       // prune threshold; exact tier-2 guards any input
// Masked-fill sentinel: largest-magnitude negative value exactly representable
// in bf16 (-3.3895314e38). Its f32->bf16 cast stays FINITE (harness compares in
// bf16 domain; -FLT_MAX rounds to -inf there -> (-inf)-(-inf)=NaN -> fail).
#define NEGF_BITS 0xFF7F0000u
#define POSF_BITS 0x7F7F0000u

// Monotone key: unsigned compare on key == float compare on value.
__device__ __forceinline__ unsigned f2k(float f) {
    unsigned u = __float_as_uint(f);
    return u ^ ((unsigned)((int)u >> 31) | 0x80000000u);
}
__device__ __forceinline__ float k2f(unsigned k) {
    unsigned m = (unsigned)((int)k >> 31);
    return __uint_as_float(k ^ (0x80000000u | ~m));
}
// Decode, clamping non-finite to sign-matched largest bf16-finite value
// (must never emit +/-inf: harness inf-inf = NaN).
__device__ __forceinline__ float k2f_finite(unsigned k) {
    float f = k2f(k);
    unsigned u = __float_as_uint(f);
    if ((u & 0x7F800000u) == 0x7F800000u)
        f = __uint_as_float((u & 0x80000000u) ? NEGF_BITS : POSF_BITS);
    return f;
}

__global__ __launch_bounds__(NTHREADS)
void topk_mask_kernel(const float* __restrict__ sim, float* __restrict__ out, int nrows) {
    const int row  = blockIdx.x;
    if (row >= nrows) return;
    const int tid  = threadIdx.x;
    const int lane = tid & 63;
    const int wid  = tid >> 6;
    const size_t rbase = (size_t)row * COLS;

    __shared__ unsigned long long s_cand[CAP];   // (key<<32) | (8191-col)
    __shared__ unsigned s_nc;
    __shared__ unsigned long long s_red[4];

    const float4* rp = (const float4*)(sim + rbase);
    float4*       op = (float4*)(out + rbase);

    // Fire-and-forget sentinel fill (no dependencies; drains at barrier 1,
    // scatter only issues after barrier 2 -> ordering safe).
    const float NEGF = __uint_as_float(NEGF_BITS);
    const float4 nf4 = make_float4(NEGF, NEGF, NEGF, NEGF);
#pragma unroll
    for (int i = 0; i < 8; ++i) op[i * NTHREADS + tid] = nf4;

    // Row -> 32 registers (coalesced float4), static indexing only.
    float f[32];
#pragma unroll
    for (int i = 0; i < 8; ++i) {
        float4 t = rp[i * NTHREADS + tid];
        f[i * 4 + 0] = t.x; f[i * 4 + 1] = t.y;
        f[i * 4 + 2] = t.z; f[i * 4 + 3] = t.w;
    }
    if (tid == 0) s_nc = 0;

    // Candidate mask: x > T (NaN-inclusive via !(x<=T)). Plain compares only.
    unsigned cmask = 0;
#pragma unroll
    for (int j = 0; j < 32; ++j)
        cmask |= (!(f[j] <= TVAL)) ? (1u << j) : 0u;

    __syncthreads();   // s_nc=0 visible; sentinel stores drained

    // Compact: ONE atomic per thread, then exec-masked unrolled writes.
    if (cmask) {
        unsigned base = atomicAdd(&s_nc, (unsigned)__popc(cmask));
#pragma unroll
        for (int j = 0; j < 32; ++j) {
            if (cmask & (1u << j)) {
                unsigned col = (unsigned)(((j >> 2) << 10) + tid * 4 + (j & 3));
                if (base < CAP)
                    s_cand[base] = ((unsigned long long)f2k(f[j]) << 32)
                                 | (unsigned)(COLS - 1 - col);
                ++base;
            }
        }
    }
    __syncthreads();
    unsigned nc = s_nc;   // block-uniform

    if (nc >= KP1 && nc <= CAP) {
        // Rank via single u64 compare (key desc, col asc == jax.lax.top_k ties);
        // LDS reads are same-address broadcasts (conflict-free).
        for (unsigned mi = tid; mi < nc; mi += NTHREADS) {
            unsigned long long me = s_cand[mi];
            unsigned r = 0;
            for (unsigned q = 0; q < nc; ++q)
                r += (s_cand[q] > me) ? 1u : 0u;
            if (r < KP1) {
                unsigned col = ((COLS - 1) - (unsigned)(me & 0xFFFFFFFFull)) & (COLS - 1);
                out[rbase + col] = k2f_finite((unsigned)(me >> 32));
            }
        }
    } else {
        // Tier 2 (exact for ANY input; statistically unreachable for Gaussian):
        // 33x block-wide max extraction over the register-resident row.
        unsigned selmask = 0;
        for (int s = 0; s < KP1; ++s) {
            unsigned long long best = 0ull;
#pragma unroll
            for (int j = 0; j < 32; ++j) {
                if (!((selmask >> j) & 1u)) {
                    unsigned col = (unsigned)(((j >> 2) << 10) + tid * 4 + (j & 3));
                    unsigned long long p =
                        ((unsigned long long)f2k(f[j]) << 32) | (0xFFFFFFFFu - col);
                    if (p > best) best = p;
                }
            }
#pragma unroll
            for (int d = 1; d < 64; d <<= 1) {
                unsigned long long o = __shfl_xor(best, d, 64);
                if (o > best) best = o;
            }
            if (lane == 0) s_red[wid] = best;
            __syncthreads();
            unsigned long long gb = s_red[0];
            if (s_red[1] > gb) gb = s_red[1];
            if (s_red[2] > gb) gb = s_red[2];
            if (s_red[3] > gb) gb = s_red[3];
            unsigned gidx = (0xFFFFFFFFu - (unsigned)(gb & 0xFFFFFFFFull)) & (COLS - 1);
            unsigned gkey = (unsigned)(gb >> 32);
            if (((gidx >> 2) & 255u) == (unsigned)tid) {   // owner thread
                unsigned j = ((gidx >> 10) << 2) | (gidx & 3u);
                selmask |= (1u << j);
                out[rbase + gidx] = k2f_finite(gkey);
            }
            __syncthreads();
        }
    }
}

extern "C" void kernel_launch(void* const* d_in, const int* in_sizes, int n_in,
                              void* d_out, int out_size, void* d_ws, size_t ws_size,
                              hipStream_t stream) {
    const float* sim = (const float*)d_in[0];
    float* out = (float*)d_out;
    int rows = in_sizes[0] / COLS;
    hipLaunchKernelGGL(topk_mask_kernel, dim3(rows), dim3(NTHREADS), 0, stream,
                       sim, out, rows);
}

// Round 8
// 106.453 us; speedup vs baseline: 1.3840x; 1.0926x over previous
//
#include <hip/hip_runtime.h>
#include <stdint.h>

#define COLS      8192
#define KP1       33          // k+1
#define CAP       1024        // candidate capacity (mean ~100 at T=2.25)
#define NTHREADS  256
#define TVAL      2.25f       // prune threshold; exact tier-2 guards any input
// Masked-fill sentinel: largest-magnitude negative value exactly representable
// in bf16 (-3.3895314e38). Its f32->bf16 cast stays FINITE (harness compares in
// bf16 domain; -FLT_MAX rounds to -inf there -> (-inf)-(-inf)=NaN -> fail).
#define NEGF_BITS 0xFF7F0000u
#define POSF_BITS 0x7F7F0000u

// Native clang vector: __builtin_nontemporal_* requires a real vector type
// (HIP's float4 is a struct wrapper and is rejected).
typedef float f32x4 __attribute__((ext_vector_type(4)));

// Monotone key: unsigned compare on key == float compare on value.
__device__ __forceinline__ unsigned f2k(float f) {
    unsigned u = __float_as_uint(f);
    return u ^ ((unsigned)((int)u >> 31) | 0x80000000u);
}
__device__ __forceinline__ float k2f(unsigned k) {
    unsigned m = (unsigned)((int)k >> 31);
    return __uint_as_float(k ^ (0x80000000u | ~m));
}
// Decode, clamping non-finite to sign-matched largest bf16-finite value
// (must never emit +/-inf: harness inf-inf = NaN).
__device__ __forceinline__ float k2f_finite(unsigned k) {
    float f = k2f(k);
    unsigned u = __float_as_uint(f);
    if ((u & 0x7F800000u) == 0x7F800000u)
        f = __uint_as_float((u & 0x80000000u) ? NEGF_BITS : POSF_BITS);
    return f;
}
__device__ __forceinline__ unsigned long long pack_cand(float v, unsigned col) {
    return ((unsigned long long)f2k(v) << 32) | (unsigned)(COLS - 1 - col);
}

// 64 VGPR cap -> 8 waves/SIMD -> 8 blocks/CU (32 waves/CU = max occupancy).
__global__ __launch_bounds__(NTHREADS, 8)
void topk_mask_kernel(const float* __restrict__ sim, float* __restrict__ out, int nrows) {
    const int row  = blockIdx.x;
    if (row >= nrows) return;
    const int tid  = threadIdx.x;
    const int lane = tid & 63;
    const int wid  = tid >> 6;
    const size_t rbase = (size_t)row * COLS;

    __shared__ unsigned long long s_cand[CAP];   // (key<<32) | (8191-col)
    __shared__ unsigned s_nc;
    __shared__ unsigned long long s_red[4];

    const f32x4* rp = (const f32x4*)(sim + rbase);
    f32x4*       op = (f32x4*)(out + rbase);

    if (tid == 0) s_nc = 0;
    __syncthreads();   // s_nc visible before any atomicAdd

    const float NEGF = __uint_as_float(NEGF_BITS);
    const f32x4 nf4 = {NEGF, NEGF, NEGF, NEGF};

    // Fused stream: load 4 elems (nt), fill sentinel (nt), compact candidates.
    // No register-resident row -> low VGPR -> 8 blocks/CU of TLP.
#pragma unroll 4
    for (int i = 0; i < 8; ++i) {
        const int idx = i * NTHREADS + tid;
        f32x4 t = __builtin_nontemporal_load(&rp[idx]);
        __builtin_nontemporal_store(nf4, &op[idx]);
        // NaN-inclusive predicate: !(x <= T)
        unsigned m4 = 0;
        m4 |= (!(t.x <= TVAL)) ? 1u : 0u;
        m4 |= (!(t.y <= TVAL)) ? 2u : 0u;
        m4 |= (!(t.z <= TVAL)) ? 4u : 0u;
        m4 |= (!(t.w <= TVAL)) ? 8u : 0u;
        if (m4) {                                    // ~5% of threads
            unsigned base = atomicAdd(&s_nc, (unsigned)__popc(m4));
            unsigned col0 = (unsigned)(i * 1024 + tid * 4);
            if (m4 & 1u) { if (base < CAP) s_cand[base] = pack_cand(t.x, col0 + 0); ++base; }
            if (m4 & 2u) { if (base < CAP) s_cand[base] = pack_cand(t.y, col0 + 1); ++base; }
            if (m4 & 4u) { if (base < CAP) s_cand[base] = pack_cand(t.z, col0 + 2); ++base; }
            if (m4 & 8u) { if (base < CAP) s_cand[base] = pack_cand(t.w, col0 + 3); ++base; }
        }
    }
    __syncthreads();   // candidates complete; sentinel stores drained (vmcnt 0)
    unsigned nc = s_nc;   // block-uniform

    if (nc >= KP1 && nc <= CAP) {
        // Rank via single u64 compare (key desc, col asc == jax.lax.top_k ties);
        // LDS reads are same-address broadcasts (conflict-free).
        for (unsigned mi = tid; mi < nc; mi += NTHREADS) {
            unsigned long long me = s_cand[mi];
            unsigned r = 0;
            for (unsigned q = 0; q < nc; ++q)
                r += (s_cand[q] > me) ? 1u : 0u;
            if (r < KP1) {
                unsigned col = ((COLS - 1) - (unsigned)(me & 0xFFFFFFFFull)) & (COLS - 1);
                out[rbase + col] = k2f_finite((unsigned)(me >> 32));
            }
        }
    } else {
        // Tier 2 (exact for ANY input; statistically unreachable for Gaussian).
        // Re-reads the row from global each pass to keep worst-case VGPRs low.
        unsigned selmask = 0;   // this thread's 32 elements, selected bits
        for (int s = 0; s < KP1; ++s) {
            unsigned long long best = 0ull;
            for (int i = 0; i < 8; ++i) {
                f32x4 t = rp[i * NTHREADS + tid];
                unsigned col0 = (unsigned)(i * 1024 + tid * 4);
                float e[4] = {t.x, t.y, t.z, t.w};
#pragma unroll
                for (int c = 0; c < 4; ++c) {
                    int j = i * 4 + c;
                    if (!((selmask >> j) & 1u)) {
                        unsigned long long p =
                            ((unsigned long long)f2k(e[c]) << 32)
                            | (0xFFFFFFFFu - (col0 + c));
                        if (p > best) best = p;
                    }
                }
            }
#pragma unroll
            for (int d = 1; d < 64; d <<= 1) {
                unsigned long long o = __shfl_xor(best, d, 64);
                if (o > best) best = o;
            }
            if (lane == 0) s_red[wid] = best;
            __syncthreads();
            unsigned long long gb = s_red[0];
            if (s_red[1] > gb) gb = s_red[1];
            if (s_red[2] > gb) gb = s_red[2];
            if (s_red[3] > gb) gb = s_red[3];
            unsigned gidx = (0xFFFFFFFFu - (unsigned)(gb & 0xFFFFFFFFull)) & (COLS - 1);
            unsigned gkey = (unsigned)(gb >> 32);
            if (((gidx >> 2) & 255u) == (unsigned)tid) {   // owner thread
                unsigned j = ((gidx >> 10) << 2) | (gidx & 3u);
                selmask |= (1u << j);
                out[rbase + gidx] = k2f_finite(gkey);
            }
            __syncthreads();
        }
    }
}

extern "C" void kernel_launch(void* const* d_in, const int* in_sizes, int n_in,
                              void* d_out, int out_size, void* d_ws, size_t ws_size,
                              hipStream_t stream) {
    const float* sim = (const float*)d_in[0];
    float* out = (float*)d_out;
    int rows = in_sizes[0] / COLS;
    hipLaunchKernelGGL(topk_mask_kernel, dim3(rows), dim3(NTHREADS), 0, stream,
                       sim, out, rows);
}

// Round 9
// 101.951 us; speedup vs baseline: 1.4451x; 1.0442x over previous
//
#include <hip/hip_runtime.h>
#include <stdint.h>

#define COLS      8192
#define KP1       33          // k+1
#define CAP       1024        // candidate capacity (mean ~100 at T=2.25)
#define NTHREADS  256
#define TVAL      2.25f       // prune threshold; exact tier-2 guards any input
// Masked-fill sentinel: largest-magnitude negative value exactly representable
// in bf16 (-3.3895314e38). Its f32->bf16 cast stays FINITE (harness compares in
// bf16 domain; -FLT_MAX rounds to -inf there -> (-inf)-(-inf)=NaN -> fail).
#define NEGF_BITS 0xFF7F0000u
#define POSF_BITS 0x7F7F0000u

// Native clang vector (__builtin_nontemporal_* rejects HIP's float4 wrapper).
typedef float f32x4 __attribute__((ext_vector_type(4)));

// Monotone key: unsigned compare on key == float compare on value.
__device__ __forceinline__ unsigned f2k(float f) {
    unsigned u = __float_as_uint(f);
    return u ^ ((unsigned)((int)u >> 31) | 0x80000000u);
}
__device__ __forceinline__ float k2f(unsigned k) {
    unsigned m = (unsigned)((int)k >> 31);
    return __uint_as_float(k ^ (0x80000000u | ~m));
}
// Decode, clamping non-finite to sign-matched largest bf16-finite value
// (must never emit +/-inf: harness inf-inf = NaN).
__device__ __forceinline__ float k2f_finite(unsigned k) {
    float f = k2f(k);
    unsigned u = __float_as_uint(f);
    if ((u & 0x7F800000u) == 0x7F800000u)
        f = __uint_as_float((u & 0x80000000u) ? NEGF_BITS : POSF_BITS);
    return f;
}
__device__ __forceinline__ unsigned long long pack_cand(float v, unsigned col) {
    return ((unsigned long long)f2k(v) << 32) | (unsigned)(COLS - 1 - col);
}

// 64 VGPR cap -> 8 waves/SIMD -> 8 blocks/CU (32 waves/CU = max occupancy).
__global__ __launch_bounds__(NTHREADS, 8)
void topk_mask_kernel(const float* __restrict__ sim, float* __restrict__ out, int nrows) {
    const int row  = blockIdx.x;
    if (row >= nrows) return;
    const int tid  = threadIdx.x;
    const int lane = tid & 63;
    const int wid  = tid >> 6;
    const size_t rbase = (size_t)row * COLS;

    __shared__ unsigned long long s_cand[CAP];   // (key<<32) | (8191-col)
    __shared__ unsigned s_nc;
    __shared__ unsigned long long s_red[4];

    const f32x4* rp = (const f32x4*)(sim + rbase);
    f32x4*       op = (f32x4*)(out + rbase);

    if (tid == 0) s_nc = 0;

    const float NEGF = __uint_as_float(NEGF_BITS);
    const f32x4 nf4 = {NEGF, NEGF, NEGF, NEGF};

    // ---- Pure stream phase: NO LDS ops in here. 8 nt loads (row -> 32 VGPRs),
    // 8 independent nt sentinel stores, compare-only mask build. Max MLP.
    f32x4 v[8];
#pragma unroll
    for (int i = 0; i < 8; ++i)
        v[i] = __builtin_nontemporal_load(&rp[i * NTHREADS + tid]);
#pragma unroll
    for (int i = 0; i < 8; ++i)
        __builtin_nontemporal_store(nf4, &op[i * NTHREADS + tid]);

    // NaN-inclusive predicate: !(x <= T).
    unsigned cmask = 0;
#pragma unroll
    for (int i = 0; i < 8; ++i) {
        cmask |= (!(v[i].x <= TVAL)) ? (1u << (4 * i + 0)) : 0u;
        cmask |= (!(v[i].y <= TVAL)) ? (1u << (4 * i + 1)) : 0u;
        cmask |= (!(v[i].z <= TVAL)) ? (1u << (4 * i + 2)) : 0u;
        cmask |= (!(v[i].w <= TVAL)) ? (1u << (4 * i + 3)) : 0u;
    }
    __syncthreads();   // s_nc=0 visible; stream stores drained (vmcnt 0)

    // ---- Compact: one LDS atomic per candidate-holding thread (~12/block),
    // register->LDS writes with fully static v[] indexing (rule #20).
    if (cmask) {
        unsigned base = atomicAdd(&s_nc, (unsigned)__popc(cmask));
#pragma unroll
        for (int i = 0; i < 8; ++i) {
            unsigned col0 = (unsigned)(i * 1024 + tid * 4);
            if (cmask & (1u << (4 * i + 0))) { if (base < CAP) s_cand[base] = pack_cand(v[i].x, col0 + 0); ++base; }
            if (cmask & (1u << (4 * i + 1))) { if (base < CAP) s_cand[base] = pack_cand(v[i].y, col0 + 1); ++base; }
            if (cmask & (1u << (4 * i + 2))) { if (base < CAP) s_cand[base] = pack_cand(v[i].z, col0 + 2); ++base; }
            if (cmask & (1u << (4 * i + 3))) { if (base < CAP) s_cand[base] = pack_cand(v[i].w, col0 + 3); ++base; }
        }
    }
    __syncthreads();
    unsigned nc = s_nc;   // block-uniform

    if (nc >= KP1 && nc <= CAP) {
        // ---- Rank (key desc, col asc == jax.lax.top_k ties) + scatter.
        // LDS reads are same-address broadcasts; unroll x4 for issue rate.
        for (unsigned mi = tid; mi < nc; mi += NTHREADS) {
            unsigned long long me = s_cand[mi];
            unsigned r = 0, q = 0, nc4 = nc & ~3u;
            for (; q < nc4; q += 4) {
                r += (s_cand[q + 0] > me) ? 1u : 0u;
                r += (s_cand[q + 1] > me) ? 1u : 0u;
                r += (s_cand[q + 2] > me) ? 1u : 0u;
                r += (s_cand[q + 3] > me) ? 1u : 0u;
            }
            for (; q < nc; ++q) r += (s_cand[q] > me) ? 1u : 0u;
            if (r < KP1) {
                unsigned col = ((COLS - 1) - (unsigned)(me & 0xFFFFFFFFull)) & (COLS - 1);
                out[rbase + col] = k2f_finite((unsigned)(me >> 32));
            }
        }
    } else {
        // ---- Tier 2 (exact for ANY input; statistically unreachable for
        // Gaussian): 33x block-wide max extraction, register-resident row.
        unsigned selmask = 0;
        for (int s = 0; s < KP1; ++s) {
            unsigned long long best = 0ull;
#pragma unroll
            for (int i = 0; i < 8; ++i) {
                float e[4] = {v[i].x, v[i].y, v[i].z, v[i].w};
                unsigned col0 = (unsigned)(i * 1024 + tid * 4);
#pragma unroll
                for (int c = 0; c < 4; ++c) {
                    int j = i * 4 + c;
                    if (!((selmask >> j) & 1u)) {
                        unsigned long long p =
                            ((unsigned long long)f2k(e[c]) << 32)
                            | (0xFFFFFFFFu - (col0 + c));
                        if (p > best) best = p;
                    }
                }
            }
#pragma unroll
            for (int d = 1; d < 64; d <<= 1) {
                unsigned long long o = __shfl_xor(best, d, 64);
                if (o > best) best = o;
            }
            if (lane == 0) s_red[wid] = best;
            __syncthreads();
            unsigned long long gb = s_red[0];
            if (s_red[1] > gb) gb = s_red[1];
            if (s_red[2] > gb) gb = s_red[2];
            if (s_red[3] > gb) gb = s_red[3];
            unsigned gidx = (0xFFFFFFFFu - (unsigned)(gb & 0xFFFFFFFFull)) & (COLS - 1);
            unsigned gkey = (unsigned)(gb >> 32);
            if (((gidx >> 2) & 255u) == (unsigned)tid) {   // owner thread
                unsigned j = ((gidx >> 10) << 2) | (gidx & 3u);
                selmask |= (1u << j);
                out[rbase + gidx] = k2f_finite(gkey);
            }
            __syncthreads();
        }
    }
}

extern "C" void kernel_launch(void* const* d_in, const int* in_sizes, int n_in,
                              void* d_out, int out_size, void* d_ws, size_t ws_size,
                              hipStream_t stream) {
    const float* sim = (const float*)d_in[0];
    float* out = (float*)d_out;
    int rows = in_sizes[0] / COLS;
    hipLaunchKernelGGL(topk_mask_kernel, dim3(rows), dim3(NTHREADS), 0, stream,
                       sim, out, rows);
}